// Round 13
// baseline (8210.474 us; speedup 1.0000x reference)
//
#include <hip/hip_runtime.h>
#include <hip/hip_cooperative_groups.h>

namespace cg = cooperative_groups;

typedef __attribute__((ext_vector_type(8))) short short8;
typedef __attribute__((ext_vector_type(4))) float f32x4;

#define NBATCH 256
#define NSTEP  128
#define NFEAT  128
#define NHID   1024
#define NOUT   128
#define KOUT   131072
#define NBLK   256

// LDS (bytes): W0h k-major [128 g][16 r] 32KB | W1 k-major [256 g][16 r] 64KB
#define W0H_OFF 0
#define W1_OFF  32768
#define SMEM_BYTES 98304

#define MFMA __builtin_amdgcn_mfma_f32_16x16x32_bf16

__device__ __forceinline__ unsigned short f2bf(float f){
  unsigned u = __float_as_uint(f);
  u += 0x7fffu + ((u >> 16) & 1u);
  return (unsigned short)(u >> 16);
}
__device__ __forceinline__ float sigf(float x){
  x = fminf(fmaxf(x, -30.f), 30.f);
  return 1.f / (1.f + __expf(-x));
}
__device__ __forceinline__ float tanhf_(float x){
  x = fminf(fmaxf(x, -15.f), 15.f);
  float e = __expf(2.f * x);
  return (e - 1.f) / (e + 1.f);
}

struct Params {
  const float *batch,*Wih0,*Whh0,*bih0,*bhh0,*Wih1,*Whh1,*bih1,*bhh1,*h00,*c00,*h01,*c01,*Wout,*bout;
  float *out;
  unsigned short *h0b,*h1b,*outs,*xbf;
  float *partial;
  unsigned *ctr;
};

__device__ __forceinline__ short8 ld8(const unsigned short* p){
  return *(const short8*)p;
}
__device__ __forceinline__ short8 ld8f(const float* p){
  f32x4 a = *(const f32x4*)p;
  f32x4 b = *(const f32x4*)(p + 4);
  short8 r;
  r[0]=(short)f2bf(a[0]); r[1]=(short)f2bf(a[1]); r[2]=(short)f2bf(a[2]); r[3]=(short)f2bf(a[3]);
  r[4]=(short)f2bf(b[0]); r[5]=(short)f2bf(b[1]); r[6]=(short)f2bf(b[2]); r[7]=(short)f2bf(b[3]);
  return r;
}

// slim grid barrier with agent-scope coherence
__device__ __forceinline__ void slim_bar(unsigned* c, int tid){
  __syncthreads();
  if (tid == 0) {
    __builtin_amdgcn_fence(__ATOMIC_RELEASE, "agent");
    __hip_atomic_fetch_add(c, 1u, __ATOMIC_RELAXED, __HIP_MEMORY_SCOPE_AGENT);
    while (__hip_atomic_load(c, __ATOMIC_RELAXED, __HIP_MEMORY_SCOPE_AGENT) < (unsigned)NBLK)
      __builtin_amdgcn_s_sleep(2);
  }
  __syncthreads();
  __builtin_amdgcn_fence(__ATOMIC_ACQUIRE, "agent");
}

__attribute__((amdgpu_waves_per_eu(2, 2)))
__global__ void __launch_bounds__(512) lstm_all(Params a)
{
  extern __shared__ char smem[];
  const int bx = blockIdx.x, tid = threadIdx.x;
  const int gtid = bx * 512 + tid, nthr = gridDim.x * 512;
  const int w = tid >> 6, l = tid & 63, lo = l & 15, hi = l >> 4;
  const int klane = hi * 8;

  // ---------------- setup ----------------
  if (bx == 0) for (int i = tid; i < 192; i += 512) a.ctr[i] = 0;
  // W0h (Whh0) -> LDS k-major: [g 0..127][row 0..15] * 16B
  for (int item = tid; item < 128 * 16; item += 512) {
    int g = item >> 4, lr = item & 15;
    int r = 16 * bx + lr, orig = (r & 3) * NHID + (r >> 2);
    *(short8*)(smem + W0H_OFF + item * 16) = ld8f(a.Whh0 + (size_t)orig * NHID + g * 8);
  }
  // W1 -> LDS k-major: [g 0..255][row 0..15] * 16B  (g<128: Wih1, g>=128: Whh1)
  for (int item = tid; item < 256 * 16; item += 512) {
    int g = item >> 4, lr = item & 15;
    int r = 16 * bx + lr, orig = (r & 3) * NHID + (r >> 2);
    int k = g * 8;
    const float* src = (k < NHID) ? a.Wih1 + (size_t)orig * NHID + k
                                  : a.Whh1 + (size_t)orig * NHID + (k - NHID);
    *(short8*)(smem + W1_OFF + item * 16) = ld8f(src);
  }
  // W0 x-segment -> registers (4 frags)
  short8 wx[4];
  {
    int r = 16 * bx + lo, orig = (r & 3) * NHID + (r >> 2);
    const float* s = a.Wih0 + (size_t)orig * NFEAT + klane;
    #pragma unroll
    for (int i = 0; i < 4; i++) wx[i] = ld8f(s + i * 32);
  }
  for (int i = gtid; i < NBATCH * NHID; i += nthr) {
    a.h0b[NBATCH * NHID + i] = f2bf(a.h00[i]);
    a.h1b[NBATCH * NHID + i] = f2bf(a.h01[i]);
  }
  for (int i = gtid; i < NSTEP * NBATCH * NFEAT / 8; i += nthr)
    *(short8*)(a.xbf + (size_t)i * 8) = ld8f(a.batch + (size_t)i * 8);

  const int j = 4 * bx + hi;
  float b0r[4], b1r[4];
  #pragma unroll
  for (int q = 0; q < 4; q++) {
    b0r[q] = a.bih0[q * NHID + j] + a.bhh0[q * NHID + j];
    b1r[q] = a.bih1[q * NHID + j] + a.bhh1[q * NHID + j];
  }
  const int m0 = w * 32 + lo, m1 = m0 + 16;
  float c0r[2], c1r[2];
  c0r[0] = a.c00[(size_t)m0 * NHID + j]; c0r[1] = a.c00[(size_t)m1 * NHID + j];
  c1r[0] = a.c01[(size_t)m0 * NHID + j]; c1r[1] = a.c01[(size_t)m1 * NHID + j];
  __syncthreads();
  cg::this_grid().sync();

  // ---------------- 129 pipelined phases ----------------
  // 68 chunks/phase, [32 k] each: 0-3 x, 4-35 h0, 36-67 h1.
  // Act goes global -> REGISTER ring (8 slots, depth-7), no LDS hop, no intra-phase barriers.
  // Compiler auto-inserts fine-grained vmcnt before each slot's first use.
  for (int p = 0; p <= NSTEP; p++) {
    const int wpar = p & 1, rp = wpar ^ 1;
    const unsigned short* h0p = a.h0b + (size_t)rp   * NBATCH * NHID;
    const unsigned short* h1p = a.h1b + (size_t)wpar * NBATCH * NHID;
    const int t0 = (p < NSTEP) ? p : (NSTEP - 1);
    // per-lane source pointers (MFMA fragment layout: row lo, k-granule hi)
    const unsigned short* xP0  = a.xbf + (size_t)t0 * NBATCH * NFEAT + (size_t)m0 * NFEAT + klane;
    const unsigned short* xP1  = xP0 + (size_t)16 * NFEAT;
    const unsigned short* h0P0 = h0p + (size_t)m0 * NHID + klane;
    const unsigned short* h0P1 = h0P0 + (size_t)16 * NHID;
    const unsigned short* h1P0 = h1p + (size_t)m0 * NHID + klane;
    const unsigned short* h1P1 = h1P0 + (size_t)16 * NHID;

    auto lda0 = [&](int cc){
      return (cc < 4) ? ld8(xP0 + cc * 32)
           : (cc < 36) ? ld8(h0P0 + (cc - 4) * 32)
                       : ld8(h1P0 + (cc - 36) * 32);
    };
    auto lda1 = [&](int cc){
      return (cc < 4) ? ld8(xP1 + cc * 32)
           : (cc < 36) ? ld8(h0P1 + (cc - 4) * 32)
                       : ld8(h1P1 + (cc - 36) * 32);
    };

    f32x4 l0a0 = {0.f,0.f,0.f,0.f}, l0a1 = {0.f,0.f,0.f,0.f};
    f32x4 l1a0 = {0.f,0.f,0.f,0.f}, l1a1 = {0.f,0.f,0.f,0.f};

    short8 ra[8], rb[8];
    #pragma unroll
    for (int q = 0; q < 7; q++) { ra[q] = lda0(q); rb[q] = lda1(q); }

    #pragma unroll
    for (int c = 0; c < 68; ++c) {
      if (c + 7 < 68) { ra[(c + 7) & 7] = lda0(c + 7); rb[(c + 7) & 7] = lda1(c + 7); }
      short8 a0 = ra[c & 7];
      short8 a1 = rb[c & 7];

      if (c < 4) {
        l0a0 = MFMA(wx[c], a0, l0a0, 0,0,0); l0a1 = MFMA(wx[c], a1, l0a1, 0,0,0);
      } else if (c < 36) {
        int g = (c - 4) * 4 + hi;
        short8 w0f = *(const short8*)(smem + W0H_OFF + g * 256 + lo * 16);
        short8 w1f = *(const short8*)(smem + W1_OFF  + g * 256 + lo * 16);
        l0a0 = MFMA(w0f, a0, l0a0, 0,0,0); l0a1 = MFMA(w0f, a1, l0a1, 0,0,0);
        l1a0 = MFMA(w1f, a0, l1a0, 0,0,0); l1a1 = MFMA(w1f, a1, l1a1, 0,0,0);
      } else {
        int g = 128 + (c - 36) * 4 + hi;
        short8 wf = *(const short8*)(smem + W1_OFF + g * 256 + lo * 16);
        l1a0 = MFMA(wf, a0, l1a0, 0,0,0); l1a1 = MFMA(wf, a1, l1a1, 0,0,0);
      }
    }

    // epilogues: lane-local cell update (gates i,f,g,o in acc[0..3])
    if (p < NSTEP) {
      unsigned short* ho = a.h0b + (size_t)wpar * NBATCH * NHID;
      float cn0 = sigf(l0a0[1] + b0r[1]) * c0r[0] + sigf(l0a0[0] + b0r[0]) * tanhf_(l0a0[2] + b0r[2]);
      c0r[0] = cn0;
      ho[(size_t)m0 * NHID + j] = f2bf(sigf(l0a0[3] + b0r[3]) * tanhf_(cn0));
      float cn1 = sigf(l0a1[1] + b0r[1]) * c0r[1] + sigf(l0a1[0] + b0r[0]) * tanhf_(l0a1[2] + b0r[2]);
      c0r[1] = cn1;
      ho[(size_t)m1 * NHID + j] = f2bf(sigf(l0a1[3] + b0r[3]) * tanhf_(cn1));
    }
    if (p >= 1) {
      unsigned short* h1o = a.h1b + (size_t)rp * NBATCH * NHID;
      unsigned short* oo  = a.outs + (size_t)(p - 1) * NBATCH * NHID;
      float cn0 = sigf(l1a0[1] + b1r[1]) * c1r[0] + sigf(l1a0[0] + b1r[0]) * tanhf_(l1a0[2] + b1r[2]);
      c1r[0] = cn0;
      unsigned short u0 = f2bf(sigf(l1a0[3] + b1r[3]) * tanhf_(cn0));
      h1o[(size_t)m0 * NHID + j] = u0; oo[(size_t)m0 * NHID + j] = u0;
      float cn1 = sigf(l1a1[1] + b1r[1]) * c1r[1] + sigf(l1a1[0] + b1r[0]) * tanhf_(l1a1[2] + b1r[2]);
      c1r[1] = cn1;
      unsigned short u1 = f2bf(sigf(l1a1[3] + b1r[3]) * tanhf_(cn1));
      h1o[(size_t)m1 * NHID + j] = u1; oo[(size_t)m1 * NHID + j] = u1;
    }
    slim_bar(a.ctr + p, tid);
  }

  cg::this_grid().sync();   // release outs + acquire for final GEMM

  // ---------------- final GEMM: out[i][o] = outs_flat[i,:] . Wout[o,:] + bout ----------------
  {
    int fnt = bx & 3, kc = bx >> 2;
    f32x4 facc[2][2];
    #pragma unroll
    for (int i = 0; i < 2; i++) { facc[i][0] = (f32x4)(0.f); facc[i][1] = (f32x4)(0.f); }
    const int kbase = kc * 2048;
    #pragma unroll 2
    for (int kk = 0; kk < 64; kk++) {
      short8 wf0 = ld8f(a.Wout + (size_t)(fnt * 32 +  0 + lo) * KOUT + kbase + kk * 32 + klane);
      short8 wf1 = ld8f(a.Wout + (size_t)(fnt * 32 + 16 + lo) * KOUT + kbase + kk * 32 + klane);
      #pragma unroll
      for (int mf = 0; mf < 2; mf++) {
        const unsigned short* ip = a.outs + (size_t)((w * 2 + mf) * 16 + lo) * KOUT + kbase + kk * 32 + klane;
        short8 af = ld8(ip);
        facc[mf][0] = MFMA(wf0, af, facc[mf][0], 0,0,0);
        facc[mf][1] = MFMA(wf1, af, facc[mf][1], 0,0,0);
      }
    }
    #pragma unroll
    for (int mf = 0; mf < 2; mf++)
      #pragma unroll
      for (int nf = 0; nf < 2; nf++)
        #pragma unroll
        for (int r = 0; r < 4; r++) {
          int o_loc = nf * 16 + 4 * hi + r;
          int i = (w * 2 + mf) * 16 + lo;
          a.partial[(size_t)(kc * 4 + fnt) * 8192 + o_loc * 256 + i] = facc[mf][nf][r];
        }
  }
  cg::this_grid().sync();

  for (int idx = gtid; idx < NBATCH * NOUT; idx += nthr) {
    int i = idx >> 7, o = idx & 127;
    float s = a.bout[o];
    #pragma unroll 4
    for (int kc2 = 0; kc2 < 64; kc2++)
      s += a.partial[(size_t)(kc2 * 4 + (o >> 5)) * 8192 + (o & 31) * 256 + i];
    a.out[idx] = s;
  }
}

extern "C" void kernel_launch(void* const* d_in, const int* in_sizes, int n_in,
                              void* d_out, int out_size, void* d_ws, size_t ws_size,
                              hipStream_t stream)
{
  (void)in_sizes; (void)n_in; (void)out_size; (void)ws_size;
  Params a;
  a.batch = (const float*)d_in[0];  a.Wih0 = (const float*)d_in[1];
  a.Whh0  = (const float*)d_in[2];  a.bih0 = (const float*)d_in[3];
  a.bhh0  = (const float*)d_in[4];  a.Wih1 = (const float*)d_in[5];
  a.Whh1  = (const float*)d_in[6];  a.bih1 = (const float*)d_in[7];
  a.bhh1  = (const float*)d_in[8];  a.h00  = (const float*)d_in[9];
  a.c00   = (const float*)d_in[10]; a.h01  = (const float*)d_in[11];
  a.c01   = (const float*)d_in[12]; a.Wout = (const float*)d_in[13];
  a.bout  = (const float*)d_in[14];
  a.out   = (float*)d_out;

  char* ws = (char*)d_ws;
  size_t off = 0;
  auto carve = [&](size_t bytes) { char* p = ws + off; off += (bytes + 255) & ~(size_t)255; return p; };
  a.h0b     = (unsigned short*)carve((size_t)2 * NBATCH * NHID * 2);
  a.h1b     = (unsigned short*)carve((size_t)2 * NBATCH * NHID * 2);
  a.outs    = (unsigned short*)carve((size_t)NSTEP * NBATCH * NHID * 2);
  a.xbf     = (unsigned short*)carve((size_t)NSTEP * NBATCH * NFEAT * 2);
  a.partial = (float*)carve((size_t)256 * 8192 * 4);
  a.ctr     = (unsigned*)carve((size_t)256 * 4);

  hipFuncSetAttribute((const void*)lstm_all, hipFuncAttributeMaxDynamicSharedMemorySize, SMEM_BYTES);

  void* kargs[] = { &a };
  hipLaunchCooperativeKernel((void*)lstm_all, dim3(256), dim3(512), kargs, SMEM_BYTES, stream);
}

// Round 14
// 7121.963 us; speedup vs baseline: 1.1528x; 1.1528x over previous
//
#include <hip/hip_runtime.h>
#include <hip/hip_cooperative_groups.h>

namespace cg = cooperative_groups;

typedef __attribute__((ext_vector_type(8))) short short8;
typedef __attribute__((ext_vector_type(4))) float f32x4;

#define NBATCH 256
#define NSTEP  128
#define NFEAT  128
#define NHID   1024
#define NOUT   128
#define KOUT   131072
#define NBLK   256

// LDS (bytes): W0h k-major [128 g][16 r] 32KB | W1 k-major [256 g][16 r] 64KB |
//              16 waves x 4 x 1KB wave-private chunk rings (64KB)
#define W0H_OFF 0
#define W1_OFF  32768
#define CH_OFF  98304
#define SMEM_BYTES 163840

#define MFMA __builtin_amdgcn_mfma_f32_16x16x32_bf16

__device__ __forceinline__ unsigned short f2bf(float f){
  unsigned u = __float_as_uint(f);
  u += 0x7fffu + ((u >> 16) & 1u);
  return (unsigned short)(u >> 16);
}
__device__ __forceinline__ float sigf(float x){
  x = fminf(fmaxf(x, -30.f), 30.f);
  return 1.f / (1.f + __expf(-x));
}
__device__ __forceinline__ float tanhf_(float x){
  x = fminf(fmaxf(x, -15.f), 15.f);
  float e = __expf(2.f * x);
  return (e - 1.f) / (e + 1.f);
}

struct Params {
  const float *batch,*Wih0,*Whh0,*bih0,*bhh0,*Wih1,*Whh1,*bih1,*bhh1,*h00,*c00,*h01,*c01,*Wout,*bout;
  float *out;
  unsigned short *h0b,*h1b,*outs,*xbf;
  float *partial;
  unsigned *ctr;
};

__device__ __forceinline__ short8 ld8(const unsigned short* p){
  return *(const short8*)p;
}
__device__ __forceinline__ short8 ld8f(const float* p){
  f32x4 a = *(const f32x4*)p;
  f32x4 b = *(const f32x4*)(p + 4);
  short8 r;
  r[0]=(short)f2bf(a[0]); r[1]=(short)f2bf(a[1]); r[2]=(short)f2bf(a[2]); r[3]=(short)f2bf(a[3]);
  r[4]=(short)f2bf(b[0]); r[5]=(short)f2bf(b[1]); r[6]=(short)f2bf(b[2]); r[7]=(short)f2bf(b[3]);
  return r;
}

// async global->LDS, 16B/lane, dest = wave-uniform base + lane*16
__device__ __forceinline__ void dma16(const void* g, void* l){
  __builtin_amdgcn_global_load_lds((const __attribute__((address_space(1))) unsigned int*)g,
                                   (__attribute__((address_space(3))) unsigned int*)l, 16, 0, 0);
}

// slim grid barrier with agent-scope coherence
__device__ __forceinline__ void slim_bar(unsigned* c, int tid){
  __syncthreads();
  if (tid == 0) {
    __builtin_amdgcn_fence(__ATOMIC_RELEASE, "agent");
    __hip_atomic_fetch_add(c, 1u, __ATOMIC_RELAXED, __HIP_MEMORY_SCOPE_AGENT);
    while (__hip_atomic_load(c, __ATOMIC_RELAXED, __HIP_MEMORY_SCOPE_AGENT) < (unsigned)NBLK)
      __builtin_amdgcn_s_sleep(2);
  }
  __syncthreads();
  __builtin_amdgcn_fence(__ATOMIC_ACQUIRE, "agent");
}

__global__ void __launch_bounds__(1024, 4) lstm_all(Params a)
{
  extern __shared__ char smem[];
  const int bx = blockIdx.x, tid = threadIdx.x;
  const int gtid = bx * 1024 + tid, nthr = gridDim.x * 1024;
  const int w = tid >> 6, l = tid & 63, lo = l & 15, hi = l >> 4;
  const int klane = hi * 8;
  // DMA source mapping (proven r12): lane l -> row l>>2 (4 contiguous lanes / 64B segment),
  // granule (l&3)^((l>>3)&3) (permutation within the segment -> coalescing intact).
  const int dR  = l >> 2;
  const int dgo = (((l & 3) ^ ((l >> 3) & 3)) & 3) * 8;

  // ---------------- setup ----------------
  if (bx == 0) for (int i = tid; i < 192; i += 1024) a.ctr[i] = 0;
  // W0h (Whh0) -> LDS k-major: [g 0..127][row 0..15] * 16B
  for (int item = tid; item < 128 * 16; item += 1024) {
    int g = item >> 4, lr = item & 15;
    int r = 16 * bx + lr, orig = (r & 3) * NHID + (r >> 2);
    *(short8*)(smem + W0H_OFF + item * 16) = ld8f(a.Whh0 + (size_t)orig * NHID + g * 8);
  }
  // W1 -> LDS k-major: [g 0..255][row 0..15] * 16B  (g<128: Wih1, g>=128: Whh1)
  for (int item = tid; item < 256 * 16; item += 1024) {
    int g = item >> 4, lr = item & 15;
    int r = 16 * bx + lr, orig = (r & 3) * NHID + (r >> 2);
    int k = g * 8;
    const float* src = (k < NHID) ? a.Wih1 + (size_t)orig * NHID + k
                                  : a.Whh1 + (size_t)orig * NHID + (k - NHID);
    *(short8*)(smem + W1_OFF + item * 16) = ld8f(src);
  }
  // W0 x-segment -> registers (4 frags, same in every wave)
  short8 wx[4];
  {
    int r = 16 * bx + lo, orig = (r & 3) * NHID + (r >> 2);
    const float* s = a.Wih0 + (size_t)orig * NFEAT + klane;
    #pragma unroll
    for (int i = 0; i < 4; i++) wx[i] = ld8f(s + i * 32);
  }
  for (int i = gtid; i < NBATCH * NHID; i += nthr) {
    a.h0b[NBATCH * NHID + i] = f2bf(a.h00[i]);
    a.h1b[NBATCH * NHID + i] = f2bf(a.h01[i]);
  }
  for (int i = gtid; i < NSTEP * NBATCH * NFEAT / 8; i += nthr)
    *(short8*)(a.xbf + (size_t)i * 8) = ld8f(a.batch + (size_t)i * 8);

  // per-lane: unit j = 4*bx + hi, batch row m0 = w*16 + lo (one m-fragment per wave)
  const int j = 4 * bx + hi;
  const int m0 = w * 16 + lo;
  float b0r[4], b1r[4];
  #pragma unroll
  for (int q = 0; q < 4; q++) {
    b0r[q] = a.bih0[q * NHID + j] + a.bhh0[q * NHID + j];
    b1r[q] = a.bih1[q * NHID + j] + a.bhh1[q * NHID + j];
  }
  float c0r = a.c00[(size_t)m0 * NHID + j];
  float c1r = a.c01[(size_t)m0 * NHID + j];
  __syncthreads();
  cg::this_grid().sync();

  // ---------------- 129 pipelined phases ----------------
  // 68 chunks/phase of [16 m][32 k] per wave (1KB): 0-3 x, 4-35 h0, 36-67 h1.
  // Wave-private ring of 4 x 1KB, depth-3 (3 DMAs in flight), per-wave vmcnt only —
  // NO intra-phase barriers (reader == DMA issuer). 4 waves/SIMD slide to hide latency.
  char* ring = smem + CH_OFF + w * 4096;
  const int rdo = lo * 64 + ((hi ^ ((lo >> 1) & 3)) << 4);  // 2-way banks = free
  for (int p = 0; p <= NSTEP; p++) {
    const int wpar = p & 1, rp = wpar ^ 1;
    const unsigned short* h0p = a.h0b + (size_t)rp   * NBATCH * NHID;
    const unsigned short* h1p = a.h1b + (size_t)wpar * NBATCH * NHID;
    const int t0 = (p < NSTEP) ? p : (NSTEP - 1);
    const unsigned short* xA  = a.xbf + (size_t)t0 * NBATCH * NFEAT + (size_t)(w * 16 + dR) * NFEAT + dgo;
    const unsigned short* h0A = h0p + (size_t)(w * 16 + dR) * NHID + dgo;
    const unsigned short* h1A = h1p + (size_t)(w * 16 + dR) * NHID + dgo;

    auto issue = [&](int cc){
      char* base = ring + (cc & 3) * 1024;
      if      (cc < 4)  dma16(xA  + cc * 32,        base);
      else if (cc < 36) dma16(h0A + (cc - 4) * 32,  base);
      else              dma16(h1A + (cc - 36) * 32, base);
    };

    f32x4 l0a0 = {0.f,0.f,0.f,0.f};
    f32x4 l1a0 = {0.f,0.f,0.f,0.f};

    issue(0); issue(1); issue(2);

    #pragma unroll
    for (int c = 0; c < 68; ++c) {
      if      (c <= 65) asm volatile("s_waitcnt vmcnt(2)" ::: "memory");
      else if (c == 66) asm volatile("s_waitcnt vmcnt(1)" ::: "memory");
      else              asm volatile("s_waitcnt vmcnt(0)" ::: "memory");
      if (c + 3 < 68) issue(c + 3);

      short8 a0 = *(const short8*)(ring + (c & 3) * 1024 + rdo);

      if (c < 4) {
        l0a0 = MFMA(wx[c], a0, l0a0, 0,0,0);
      } else if (c < 36) {
        int g = (c - 4) * 4 + hi;
        short8 w0f = *(const short8*)(smem + W0H_OFF + g * 256 + lo * 16);
        short8 w1f = *(const short8*)(smem + W1_OFF  + g * 256 + lo * 16);
        l0a0 = MFMA(w0f, a0, l0a0, 0,0,0);
        l1a0 = MFMA(w1f, a0, l1a0, 0,0,0);
      } else {
        int g = 128 + (c - 36) * 4 + hi;
        short8 wf = *(const short8*)(smem + W1_OFF + g * 256 + lo * 16);
        l1a0 = MFMA(wf, a0, l1a0, 0,0,0);
      }
    }

    // epilogues: lane-local cell update (gates i,f,g,o in acc[0..3])
    if (p < NSTEP) {
      unsigned short* ho = a.h0b + (size_t)wpar * NBATCH * NHID;
      float cn = sigf(l0a0[1] + b0r[1]) * c0r + sigf(l0a0[0] + b0r[0]) * tanhf_(l0a0[2] + b0r[2]);
      c0r = cn;
      ho[(size_t)m0 * NHID + j] = f2bf(sigf(l0a0[3] + b0r[3]) * tanhf_(cn));
    }
    if (p >= 1) {
      unsigned short* h1o = a.h1b + (size_t)rp * NBATCH * NHID;
      unsigned short* oo  = a.outs + (size_t)(p - 1) * NBATCH * NHID;
      float cn = sigf(l1a0[1] + b1r[1]) * c1r + sigf(l1a0[0] + b1r[0]) * tanhf_(l1a0[2] + b1r[2]);
      c1r = cn;
      unsigned short u = f2bf(sigf(l1a0[3] + b1r[3]) * tanhf_(cn));
      h1o[(size_t)m0 * NHID + j] = u; oo[(size_t)m0 * NHID + j] = u;
    }
    slim_bar(a.ctr + p, tid);
  }

  cg::this_grid().sync();   // release outs + acquire for final GEMM

  // ---------------- final GEMM: out[i][o] = outs_flat[i,:] . Wout[o,:] + bout ----------------
  {
    int fnt = bx & 3, kc = bx >> 2;    // 4 o-tiles x 64 k-chunks of 2048
    f32x4 facc[2];
    facc[0] = (f32x4)(0.f); facc[1] = (f32x4)(0.f);
    const int kbase = kc * 2048;
    #pragma unroll 2
    for (int kk = 0; kk < 64; kk++) {
      short8 wf0 = ld8f(a.Wout + (size_t)(fnt * 32 +  0 + lo) * KOUT + kbase + kk * 32 + klane);
      short8 wf1 = ld8f(a.Wout + (size_t)(fnt * 32 + 16 + lo) * KOUT + kbase + kk * 32 + klane);
      const unsigned short* ip = a.outs + (size_t)(w * 16 + lo) * KOUT + kbase + kk * 32 + klane;
      short8 af = ld8(ip);
      facc[0] = MFMA(wf0, af, facc[0], 0,0,0);
      facc[1] = MFMA(wf1, af, facc[1], 0,0,0);
    }
    #pragma unroll
    for (int nf = 0; nf < 2; nf++)
      #pragma unroll
      for (int r = 0; r < 4; r++) {
        int o_loc = nf * 16 + 4 * hi + r;
        int i = w * 16 + lo;
        a.partial[(size_t)(kc * 4 + fnt) * 8192 + o_loc * 256 + i] = facc[nf][r];
      }
  }
  cg::this_grid().sync();

  for (int idx = gtid; idx < NBATCH * NOUT; idx += nthr) {
    int i = idx >> 7, o = idx & 127;
    float s = a.bout[o];
    #pragma unroll 4
    for (int kc2 = 0; kc2 < 64; kc2++)
      s += a.partial[(size_t)(kc2 * 4 + (o >> 5)) * 8192 + (o & 31) * 256 + i];
    a.out[idx] = s;
  }
}

extern "C" void kernel_launch(void* const* d_in, const int* in_sizes, int n_in,
                              void* d_out, int out_size, void* d_ws, size_t ws_size,
                              hipStream_t stream)
{
  (void)in_sizes; (void)n_in; (void)out_size; (void)ws_size;
  Params a;
  a.batch = (const float*)d_in[0];  a.Wih0 = (const float*)d_in[1];
  a.Whh0  = (const float*)d_in[2];  a.bih0 = (const float*)d_in[3];
  a.bhh0  = (const float*)d_in[4];  a.Wih1 = (const float*)d_in[5];
  a.Whh1  = (const float*)d_in[6];  a.bih1 = (const float*)d_in[7];
  a.bhh1  = (const float*)d_in[8];  a.h00  = (const float*)d_in[9];
  a.c00   = (const float*)d_in[10]; a.h01  = (const float*)d_in[11];
  a.c01   = (const float*)d_in[12]; a.Wout = (const float*)d_in[13];
  a.bout  = (const float*)d_in[14];
  a.out   = (float*)d_out;

  char* ws = (char*)d_ws;
  size_t off = 0;
  auto carve = [&](size_t bytes) { char* p = ws + off; off += (bytes + 255) & ~(size_t)255; return p; };
  a.h0b     = (unsigned short*)carve((size_t)2 * NBATCH * NHID * 2);
  a.h1b     = (unsigned short*)carve((size_t)2 * NBATCH * NHID * 2);
  a.outs    = (unsigned short*)carve((size_t)NSTEP * NBATCH * NHID * 2);
  a.xbf     = (unsigned short*)carve((size_t)NSTEP * NBATCH * NFEAT * 2);
  a.partial = (float*)carve((size_t)256 * 8192 * 4);
  a.ctr     = (unsigned*)carve((size_t)256 * 4);

  hipFuncSetAttribute((const void*)lstm_all, hipFuncAttributeMaxDynamicSharedMemorySize, SMEM_BYTES);

  void* kargs[] = { &a };
  hipLaunchCooperativeKernel((void*)lstm_all, dim3(256), dim3(1024), kargs, SMEM_BYTES, stream);
}

// Round 15
// 4990.745 us; speedup vs baseline: 1.6451x; 1.4270x over previous
//
#include <hip/hip_runtime.h>
#include <hip/hip_cooperative_groups.h>

namespace cg = cooperative_groups;

typedef __attribute__((ext_vector_type(8))) short short8;
typedef __attribute__((ext_vector_type(4))) float f32x4;

#define NBATCH 256
#define NSTEP  128
#define NFEAT  128
#define NHID   1024
#define NOUT   128
#define KOUT   131072
#define NBLK   256

// LDS (bytes): W0h k-major [128 g][16 r] 32KB | W1 k-major [256 g][16 r] 64KB | 4 chunk bufs x 16KB
#define W0H_OFF 0
#define W1_OFF  32768
#define CH_OFF  98304
#define SMEM_BYTES 163840

// tree barrier: per phase 272 u32 (16 leaf counters 64B apart + root)
#define CTR_STRIDE 272
#define CTR_TOTAL  (129 * CTR_STRIDE)

#define MFMA __builtin_amdgcn_mfma_f32_16x16x32_bf16

__device__ __forceinline__ unsigned short f2bf(float f){
  unsigned u = __float_as_uint(f);
  u += 0x7fffu + ((u >> 16) & 1u);
  return (unsigned short)(u >> 16);
}
__device__ __forceinline__ float sigf(float x){
  x = fminf(fmaxf(x, -30.f), 30.f);
  return 1.f / (1.f + __expf(-x));
}
__device__ __forceinline__ float tanhf_(float x){
  x = fminf(fmaxf(x, -15.f), 15.f);
  float e = __expf(2.f * x);
  return (e - 1.f) / (e + 1.f);
}

struct Params {
  const float *batch,*Wih0,*Whh0,*bih0,*bhh0,*Wih1,*Whh1,*bih1,*bhh1,*h00,*c00,*h01,*c01,*Wout,*bout;
  float *out;
  unsigned short *h0b,*h1b,*outs,*xbf;
  float *partial;
  unsigned *ctr;
};

__device__ __forceinline__ short8 ld8(const unsigned short* p){
  return *(const short8*)p;
}
__device__ __forceinline__ short8 ld8f(const float* p){
  f32x4 a = *(const f32x4*)p;
  f32x4 b = *(const f32x4*)(p + 4);
  short8 r;
  r[0]=(short)f2bf(a[0]); r[1]=(short)f2bf(a[1]); r[2]=(short)f2bf(a[2]); r[3]=(short)f2bf(a[3]);
  r[4]=(short)f2bf(b[0]); r[5]=(short)f2bf(b[1]); r[6]=(short)f2bf(b[2]); r[7]=(short)f2bf(b[3]);
  return r;
}

// async global->LDS, 16B/lane, dest = wave-uniform base + lane*16
__device__ __forceinline__ void dma16(const void* g, void* l){
  __builtin_amdgcn_global_load_lds((const __attribute__((address_space(1))) unsigned int*)g,
                                   (__attribute__((address_space(3))) unsigned int*)l, 16, 0, 0);
}

// pack the 4 hi-lanes' 2B h values (same lo) into one 8B little-endian word
__device__ __forceinline__ unsigned long long pack4(unsigned short u){
  unsigned v = (unsigned)u | ((unsigned)(unsigned short)__shfl_xor((int)(unsigned)u, 16) << 16);
  unsigned hi32 = (unsigned)__shfl_xor((int)v, 32);
  return (unsigned long long)v | ((unsigned long long)hi32 << 32);
}
__device__ __forceinline__ void st8a(unsigned short* p, unsigned long long v){
  __hip_atomic_store((unsigned long long*)p, v, __ATOMIC_RELAXED, __HIP_MEMORY_SCOPE_AGENT);
}

// two-level tree barrier; acquire-inv only (no dirty L2 anywhere in the loop)
__device__ __forceinline__ void tree_bar(unsigned* base, int bx, int tid){
  asm volatile("s_waitcnt vmcnt(0)" ::: "memory");   // drain this block's write-through stores
  __syncthreads();
  if (tid == 0) {
    unsigned old = __hip_atomic_fetch_add(base + (bx & 15) * 16, 1u,
                                          __ATOMIC_RELAXED, __HIP_MEMORY_SCOPE_AGENT);
    if (old == 15u)
      __hip_atomic_fetch_add(base + 256, 1u, __ATOMIC_RELAXED, __HIP_MEMORY_SCOPE_AGENT);
    while (__hip_atomic_load(base + 256, __ATOMIC_RELAXED, __HIP_MEMORY_SCOPE_AGENT) < 16u)
      __builtin_amdgcn_s_sleep(1);
  }
  __syncthreads();
  __builtin_amdgcn_fence(__ATOMIC_ACQUIRE, "agent");  // invalidate stale L1/L2
}

__global__ void __launch_bounds__(512, 2) lstm_all(Params a)
{
  extern __shared__ char smem[];
  const int bx = blockIdx.x, tid = threadIdx.x;
  const int gtid = bx * 512 + tid, nthr = gridDim.x * 512;
  const int w = tid >> 6, l = tid & 63, lo = l & 15, hi = l >> 4;
  const int klane = hi * 8;
  // DMA source mapping (r12-proven): lane l -> row l>>2 (4 contiguous lanes / 64B segment),
  // granule (l&3)^((l>>3)&3) (permutation within the segment -> coalescing intact).
  const int dR  = l >> 2;
  const int dgo = (((l & 3) ^ ((l >> 3) & 3)) & 3) * 8;

  // ---------------- setup ----------------
  for (int i = gtid; i < CTR_TOTAL; i += nthr) a.ctr[i] = 0;
  // W0h (Whh0) -> LDS k-major: [g 0..127][row 0..15] * 16B
  for (int item = tid; item < 128 * 16; item += 512) {
    int g = item >> 4, lr = item & 15;
    int r = 16 * bx + lr, orig = (r & 3) * NHID + (r >> 2);
    *(short8*)(smem + W0H_OFF + item * 16) = ld8f(a.Whh0 + (size_t)orig * NHID + g * 8);
  }
  // W1 -> LDS k-major: [g 0..255][row 0..15] * 16B  (g<128: Wih1, g>=128: Whh1)
  for (int item = tid; item < 256 * 16; item += 512) {
    int g = item >> 4, lr = item & 15;
    int r = 16 * bx + lr, orig = (r & 3) * NHID + (r >> 2);
    int k = g * 8;
    const float* src = (k < NHID) ? a.Wih1 + (size_t)orig * NHID + k
                                  : a.Whh1 + (size_t)orig * NHID + (k - NHID);
    *(short8*)(smem + W1_OFF + item * 16) = ld8f(src);
  }
  // W0 x-segment -> registers (4 frags)
  short8 wx[4];
  {
    int r = 16 * bx + lo, orig = (r & 3) * NHID + (r >> 2);
    const float* s = a.Wih0 + (size_t)orig * NFEAT + klane;
    #pragma unroll
    for (int i = 0; i < 4; i++) wx[i] = ld8f(s + i * 32);
  }
  for (int i = gtid; i < NBATCH * NHID; i += nthr) {
    a.h0b[NBATCH * NHID + i] = f2bf(a.h00[i]);
    a.h1b[NBATCH * NHID + i] = f2bf(a.h01[i]);
  }
  for (int i = gtid; i < NSTEP * NBATCH * NFEAT / 8; i += nthr)
    *(short8*)(a.xbf + (size_t)i * 8) = ld8f(a.batch + (size_t)i * 8);

  const int j = 4 * bx + hi;
  float b0r[4], b1r[4];
  #pragma unroll
  for (int q = 0; q < 4; q++) {
    b0r[q] = a.bih0[q * NHID + j] + a.bhh0[q * NHID + j];
    b1r[q] = a.bih1[q * NHID + j] + a.bhh1[q * NHID + j];
  }
  const int m0 = w * 32 + lo, m1 = m0 + 16;
  float c0r[2], c1r[2];
  c0r[0] = a.c00[(size_t)m0 * NHID + j]; c0r[1] = a.c00[(size_t)m1 * NHID + j];
  c1r[0] = a.c01[(size_t)m0 * NHID + j]; c1r[1] = a.c01[(size_t)m1 * NHID + j];
  __syncthreads();
  cg::this_grid().sync();   // full release: setup writes (plain) written back

  // ---------------- 129 pipelined phases ----------------
  // 68 chunks/phase of [32 m][32 k]/wave: 0-3 x, 4-35 h0, 36-67 h1.
  // 4 buffers, depth-3 (6 DMAs in flight), counted vmcnt + s_barrier per chunk (r7/r12-proven).
  const int rdo = lo * 64 + ((hi ^ ((lo >> 1) & 3)) << 4);  // 2-way banks = free
  for (int p = 0; p <= NSTEP; p++) {
    const int wpar = p & 1, rp = wpar ^ 1;
    const unsigned short* h0p = a.h0b + (size_t)rp   * NBATCH * NHID;
    const unsigned short* h1p = a.h1b + (size_t)wpar * NBATCH * NHID;
    const int t0 = (p < NSTEP) ? p : (NSTEP - 1);
    const unsigned short* xA  = a.xbf + (size_t)t0 * NBATCH * NFEAT + (size_t)(w * 32 + dR) * NFEAT + dgo;
    const unsigned short* h0A = h0p + (size_t)(w * 32 + dR) * NHID + dgo;
    const unsigned short* h1A = h1p + (size_t)(w * 32 + dR) * NHID + dgo;

    auto issue = [&](int cc){
      char* base = smem + CH_OFF + (cc & 3) * 16384 + w * 2048;
      if (cc < 4) {
        int ko = cc * 32;
        dma16(xA + ko, base); dma16(xA + 16 * NFEAT + ko, base + 1024);
      } else if (cc < 36) {
        int ko = (cc - 4) * 32;
        dma16(h0A + ko, base); dma16(h0A + 16 * NHID + ko, base + 1024);
      } else {
        int ko = (cc - 36) * 32;
        dma16(h1A + ko, base); dma16(h1A + 16 * NHID + ko, base + 1024);
      }
    };

    f32x4 l0a0 = {0.f,0.f,0.f,0.f}, l0a1 = {0.f,0.f,0.f,0.f};
    f32x4 l1a0 = {0.f,0.f,0.f,0.f}, l1a1 = {0.f,0.f,0.f,0.f};

    issue(0); issue(1); issue(2);

    #pragma unroll
    for (int c = 0; c < 68; ++c) {
      if      (c <= 65) asm volatile("s_waitcnt vmcnt(4)\n\ts_barrier" ::: "memory");
      else if (c == 66) asm volatile("s_waitcnt vmcnt(2)\n\ts_barrier" ::: "memory");
      else              asm volatile("s_waitcnt vmcnt(0)\n\ts_barrier" ::: "memory");
      if (c + 3 < 68) issue(c + 3);

      const char* cb = smem + CH_OFF + (c & 3) * 16384 + w * 2048;
      short8 a0 = *(const short8*)(cb + rdo);
      short8 a1 = *(const short8*)(cb + 1024 + rdo);

      if (c < 4) {
        l0a0 = MFMA(wx[c], a0, l0a0, 0,0,0); l0a1 = MFMA(wx[c], a1, l0a1, 0,0,0);
      } else if (c < 36) {
        int g = (c - 4) * 4 + hi;
        short8 w0f = *(const short8*)(smem + W0H_OFF + g * 256 + lo * 16);
        short8 w1f = *(const short8*)(smem + W1_OFF  + g * 256 + lo * 16);
        l0a0 = MFMA(w0f, a0, l0a0, 0,0,0); l0a1 = MFMA(w0f, a1, l0a1, 0,0,0);
        l1a0 = MFMA(w1f, a0, l1a0, 0,0,0); l1a1 = MFMA(w1f, a1, l1a1, 0,0,0);
      } else {
        int g = 128 + (c - 36) * 4 + hi;
        short8 wf = *(const short8*)(smem + W1_OFF + g * 256 + lo * 16);
        l1a0 = MFMA(wf, a0, l1a0, 0,0,0); l1a1 = MFMA(wf, a1, l1a1, 0,0,0);
      }
    }

    // epilogues: lane-local cell update; shuffle-pack to 8B write-through stores (no dirty L2)
    if (p < NSTEP) {
      unsigned short* ho = a.h0b + (size_t)wpar * NBATCH * NHID;
      float cn0 = sigf(l0a0[1] + b0r[1]) * c0r[0] + sigf(l0a0[0] + b0r[0]) * tanhf_(l0a0[2] + b0r[2]);
      c0r[0] = cn0;
      unsigned short hb0 = f2bf(sigf(l0a0[3] + b0r[3]) * tanhf_(cn0));
      float cn1 = sigf(l0a1[1] + b0r[1]) * c0r[1] + sigf(l0a1[0] + b0r[0]) * tanhf_(l0a1[2] + b0r[2]);
      c0r[1] = cn1;
      unsigned short hb1 = f2bf(sigf(l0a1[3] + b0r[3]) * tanhf_(cn1));
      unsigned long long pk0 = pack4(hb0), pk1 = pack4(hb1);
      if (hi == 0) {
        st8a(ho + (size_t)m0 * NHID + 4 * bx, pk0);
        st8a(ho + (size_t)m1 * NHID + 4 * bx, pk1);
      }
    }
    if (p >= 1) {
      unsigned short* h1o = a.h1b + (size_t)rp * NBATCH * NHID;
      unsigned short* oo  = a.outs + (size_t)(p - 1) * NBATCH * NHID;
      float cn0 = sigf(l1a0[1] + b1r[1]) * c1r[0] + sigf(l1a0[0] + b1r[0]) * tanhf_(l1a0[2] + b1r[2]);
      c1r[0] = cn0;
      unsigned short hb0 = f2bf(sigf(l1a0[3] + b1r[3]) * tanhf_(cn0));
      float cn1 = sigf(l1a1[1] + b1r[1]) * c1r[1] + sigf(l1a1[0] + b1r[0]) * tanhf_(l1a1[2] + b1r[2]);
      c1r[1] = cn1;
      unsigned short hb1 = f2bf(sigf(l1a1[3] + b1r[3]) * tanhf_(cn1));
      unsigned long long pk0 = pack4(hb0), pk1 = pack4(hb1);
      if (hi == 0) {
        st8a(h1o + (size_t)m0 * NHID + 4 * bx, pk0);
        st8a(h1o + (size_t)m1 * NHID + 4 * bx, pk1);
        st8a(oo  + (size_t)m0 * NHID + 4 * bx, pk0);
        st8a(oo  + (size_t)m1 * NHID + 4 * bx, pk1);
      }
    }
    tree_bar(a.ctr + p * CTR_STRIDE, bx, tid);
  }

  cg::this_grid().sync();   // full sync before final GEMM

  // ---------------- final GEMM: out[i][o] = outs_flat[i,:] . Wout[o,:] + bout ----------------
  {
    int fnt = bx & 3, kc = bx >> 2;
    f32x4 facc[2][2];
    #pragma unroll
    for (int i = 0; i < 2; i++) { facc[i][0] = (f32x4)(0.f); facc[i][1] = (f32x4)(0.f); }
    const int kbase = kc * 2048;
    #pragma unroll 2
    for (int kk = 0; kk < 64; kk++) {
      short8 wf0 = ld8f(a.Wout + (size_t)(fnt * 32 +  0 + lo) * KOUT + kbase + kk * 32 + klane);
      short8 wf1 = ld8f(a.Wout + (size_t)(fnt * 32 + 16 + lo) * KOUT + kbase + kk * 32 + klane);
      #pragma unroll
      for (int mf = 0; mf < 2; mf++) {
        const unsigned short* ip = a.outs + (size_t)((w * 2 + mf) * 16 + lo) * KOUT + kbase + kk * 32 + klane;
        short8 af = ld8(ip);
        facc[mf][0] = MFMA(wf0, af, facc[mf][0], 0,0,0);
        facc[mf][1] = MFMA(wf1, af, facc[mf][1], 0,0,0);
      }
    }
    #pragma unroll
    for (int mf = 0; mf < 2; mf++)
      #pragma unroll
      for (int nf = 0; nf < 2; nf++)
        #pragma unroll
        for (int r = 0; r < 4; r++) {
          int o_loc = nf * 16 + 4 * hi + r;
          int i = (w * 2 + mf) * 16 + lo;
          a.partial[(size_t)(kc * 4 + fnt) * 8192 + o_loc * 256 + i] = facc[mf][nf][r];
        }
  }
  cg::this_grid().sync();

  for (int idx = gtid; idx < NBATCH * NOUT; idx += nthr) {
    int i = idx >> 7, o = idx & 127;
    float s = a.bout[o];
    #pragma unroll 4
    for (int kc2 = 0; kc2 < 64; kc2++)
      s += a.partial[(size_t)(kc2 * 4 + (o >> 5)) * 8192 + (o & 31) * 256 + i];
    a.out[idx] = s;
  }
}

extern "C" void kernel_launch(void* const* d_in, const int* in_sizes, int n_in,
                              void* d_out, int out_size, void* d_ws, size_t ws_size,
                              hipStream_t stream)
{
  (void)in_sizes; (void)n_in; (void)out_size; (void)ws_size;
  Params a;
  a.batch = (const float*)d_in[0];  a.Wih0 = (const float*)d_in[1];
  a.Whh0  = (const float*)d_in[2];  a.bih0 = (const float*)d_in[3];
  a.bhh0  = (const float*)d_in[4];  a.Wih1 = (const float*)d_in[5];
  a.Whh1  = (const float*)d_in[6];  a.bih1 = (const float*)d_in[7];
  a.bhh1  = (const float*)d_in[8];  a.h00  = (const float*)d_in[9];
  a.c00   = (const float*)d_in[10]; a.h01  = (const float*)d_in[11];
  a.c01   = (const float*)d_in[12]; a.Wout = (const float*)d_in[13];
  a.bout  = (const float*)d_in[14];
  a.out   = (float*)d_out;

  char* ws = (char*)d_ws;
  size_t off = 0;
  auto carve = [&](size_t bytes) { char* p = ws + off; off += (bytes + 255) & ~(size_t)255; return p; };
  a.h0b     = (unsigned short*)carve((size_t)2 * NBATCH * NHID * 2);
  a.h1b     = (unsigned short*)carve((size_t)2 * NBATCH * NHID * 2);
  a.outs    = (unsigned short*)carve((size_t)NSTEP * NBATCH * NHID * 2);
  a.xbf     = (unsigned short*)carve((size_t)NSTEP * NBATCH * NFEAT * 2);
  a.partial = (float*)carve((size_t)256 * 8192 * 4);
  a.ctr     = (unsigned*)carve((size_t)CTR_TOTAL * 4);

  hipFuncSetAttribute((const void*)lstm_all, hipFuncAttributeMaxDynamicSharedMemorySize, SMEM_BYTES);

  void* kargs[] = { &a };
  hipLaunchCooperativeKernel((void*)lstm_all, dim3(256), dim3(512), kargs, SMEM_BYTES, stream);
}